// Round 2
// baseline (163.535 us; speedup 1.0000x reference)
//
#include <hip/hip_runtime.h>
#include <math.h>

// Problem constants
#define NB 131072
#define NC 128
#define NE 128
__device__ constexpr float S_    = 100.0f;
__device__ constexpr float COSM_ = 0.5403023058681398f;   // cos(1)
__device__ constexpr float SINM_ = 0.8414709848078965f;   // sin(1)
__device__ constexpr float TH_   = -0.5403023058681398f;  // cos(pi-1)
__device__ constexpr float MM_   = 0.8414709848078965f;   // sin(pi-1)*1

using short8 = __attribute__((ext_vector_type(8))) short;
using f32x4  = __attribute__((ext_vector_type(4))) float;

// fp32 -> bf16 (RNE) on raw bits
__device__ __forceinline__ unsigned int bf1(float f) {
    unsigned int u = __float_as_uint(f);
    return (u + 0x7FFFu + ((u >> 16) & 1u)) >> 16;
}

// Kernel 1: normalize weight rows -> bf16 (packed 2/uint) in ws; zero d_out.
__global__ void wnorm_kernel(const float* __restrict__ w,
                             unsigned int* __restrict__ wn,
                             float* __restrict__ out) {
    const int row = blockIdx.x;      // 128 rows
    const int lane = threadIdx.x;    // 64 lanes
    float2 v = ((const float2*)w)[row * 64 + lane];
    float ss = v.x * v.x + v.y * v.y;
    #pragma unroll
    for (int m = 1; m < 64; m <<= 1) ss += __shfl_xor(ss, m, 64);
    float sc = 1.0f / fmaxf(sqrtf(ss), 1e-12f);
    wn[row * 64 + lane] = bf1(v.x * sc) | (bf1(v.y * sc) << 16);
    if (row == 0 && lane == 0) *out = 0.0f;
}

// Kernel 2: fused normalize + cosine GEMM (bf16 MFMA) + arc-margin + NLL + mean
__global__ __launch_bounds__(256, 2)
void arcloss_kernel(const float* __restrict__ predict,
                    const float* __restrict__ target,
                    const unsigned int* __restrict__ wn,
                    float* __restrict__ out) {
    constexpr int PITCH = 136;  // ushorts per LDS row (272 B: 256 B data + 16 B pad)
    __shared__ __align__(16) unsigned short sp[128 * PITCH]; // pn tile, bf16
    __shared__ __align__(16) unsigned short sw[128 * PITCH]; // wn, bf16
    __shared__ int   slab[128];
    __shared__ float swsum[4];

    const int t    = threadIdx.x;
    const int lane = t & 63;
    const int wv   = t >> 6;           // wave 0..3
    const long rowbase = (long)blockIdx.x * 128;

    // ---- Stage wn (32 KB, L2-hot) into LDS with pad ----
    // 256 threads, 2 per row; each thread copies 32 uints = 8 uint4s.
    {
        int row = t >> 1, half = t & 1;
        const uint4* src = (const uint4*)(wn + row * 64 + half * 32);
        uint4* dst = (uint4*)(sw + row * PITCH + half * 64);
        #pragma unroll
        for (int j = 0; j < 8; ++j) dst[j] = src[j];
    }

    // ---- Load predict tile, L2-normalize rows, bf16 -> LDS; find labels ----
    {
        const int sub = t & 3;   // 4 threads per row
        const int r0  = t >> 2;  // 0..63
        #pragma unroll
        for (int rb = 0; rb < 2; ++rb) {
            const int row = rb * 64 + r0;
            const float4* prow = (const float4*)(predict + (rowbase + row) * NE);
            float4 x[8];
            #pragma unroll
            for (int i = 0; i < 8; ++i) x[i] = prow[i * 4 + sub];
            float ss = 0.0f;
            #pragma unroll
            for (int i = 0; i < 8; ++i)
                ss += x[i].x * x[i].x + x[i].y * x[i].y + x[i].z * x[i].z + x[i].w * x[i].w;
            ss += __shfl_xor(ss, 1, 64);
            ss += __shfl_xor(ss, 2, 64);
            const float sc = 1.0f / fmaxf(sqrtf(ss), 1e-12f);
            #pragma unroll
            for (int i = 0; i < 8; ++i) {
                unsigned int lo = bf1(x[i].x * sc) | (bf1(x[i].y * sc) << 16);
                unsigned int hi = bf1(x[i].z * sc) | (bf1(x[i].w * sc) << 16);
                *(uint2*)(sp + row * PITCH + i * 16 + sub * 4) = make_uint2(lo, hi);
            }
            // label = argmax(one-hot target row)
            const float4* trow = (const float4*)(target + (rowbase + row) * NC);
            int lab = -1;
            #pragma unroll
            for (int i = 0; i < 8; ++i) {
                float4 tv = trow[i * 4 + sub];
                int c0 = (i * 4 + sub) * 4;
                if (tv.x > 0.5f) lab = c0;
                if (tv.y > 0.5f) lab = c0 + 1;
                if (tv.z > 0.5f) lab = c0 + 2;
                if (tv.w > 0.5f) lab = c0 + 3;
            }
            lab = max(lab, __shfl_xor(lab, 1, 64));
            lab = max(lab, __shfl_xor(lab, 2, 64));
            if (sub == 0) slab[row] = lab;
        }
    }
    __syncthreads();

    // ---- MFMA: each wave computes 32 rows x 128 classes ----
    const int l15  = lane & 15;
    const int quad = lane >> 4;
    f32x4 acc[2][8];
    #pragma unroll
    for (int rt = 0; rt < 2; ++rt)
        #pragma unroll
        for (int tc = 0; tc < 8; ++tc)
            acc[rt][tc] = (f32x4){0.f, 0.f, 0.f, 0.f};

    #pragma unroll
    for (int kc = 0; kc < 4; ++kc) {
        short8 a[2], b[8];
        #pragma unroll
        for (int rt = 0; rt < 2; ++rt)
            a[rt] = *(const short8*)(sp + (wv * 32 + rt * 16 + l15) * PITCH + kc * 32 + quad * 8);
        #pragma unroll
        for (int tc = 0; tc < 8; ++tc)
            b[tc] = *(const short8*)(sw + (tc * 16 + l15) * PITCH + kc * 32 + quad * 8);
        #pragma unroll
        for (int rt = 0; rt < 2; ++rt)
            #pragma unroll
            for (int tc = 0; tc < 8; ++tc)
                acc[rt][tc] = __builtin_amdgcn_mfma_f32_16x16x32_bf16(a[rt], b[tc], acc[rt][tc], 0, 0, 0);
    }

    // ---- Epilogue: margin transform + stable logsumexp per row ----
    float lsum = 0.0f;
    #pragma unroll
    for (int rt = 0; rt < 2; ++rt) {
        #pragma unroll
        for (int v = 0; v < 4; ++v) {
            const int row = wv * 32 + rt * 16 + quad * 4 + v;  // C/D: row = quad*4+reg
            const int lab = slab[row];
            float mx = -1e30f, labv = 0.0f;
            float lg[8];
            #pragma unroll
            for (int tc = 0; tc < 8; ++tc) {
                float c = acc[rt][tc][v];
                int cls = tc * 16 + l15;                       // C/D: col = lane&15
                float s2 = fmaxf(1.0f - c * c, 0.0f);
                float ph = c * COSM_ - sqrtf(s2) * SINM_;
                ph = (c > TH_) ? ph : (c - MM_);
                float L = S_ * ((cls == lab) ? ph : c);
                lg[tc] = L;
                mx = fmaxf(mx, L);
                if (cls == lab) labv = L;
            }
            #pragma unroll
            for (int m = 1; m < 16; m <<= 1) mx = fmaxf(mx, __shfl_xor(mx, m, 64));
            float se = 0.0f;
            #pragma unroll
            for (int tc = 0; tc < 8; ++tc) se += __expf(lg[tc] - mx);
            #pragma unroll
            for (int m = 1; m < 16; m <<= 1) {
                se   += __shfl_xor(se, m, 64);
                labv += __shfl_xor(labv, m, 64);
            }
            if (l15 == 0) lsum += __logf(se) + mx - labv;
        }
    }

    // ---- Block reduction + one atomic per block ----
    #pragma unroll
    for (int m = 1; m < 64; m <<= 1) lsum += __shfl_xor(lsum, m, 64);
    if (lane == 0) swsum[wv] = lsum;
    __syncthreads();
    if (t == 0) {
        float tot = swsum[0] + swsum[1] + swsum[2] + swsum[3];
        atomicAdd(out, tot * (1.0f / (float)NB));
    }
}

extern "C" void kernel_launch(void* const* d_in, const int* in_sizes, int n_in,
                              void* d_out, int out_size, void* d_ws, size_t ws_size,
                              hipStream_t stream) {
    const float* predict = (const float*)d_in[0];
    const float* target  = (const float*)d_in[1];
    const float* weight  = (const float*)d_in[2];
    float* out = (float*)d_out;
    unsigned int* wn = (unsigned int*)d_ws;  // 128*64 uints = 32 KB bf16 wn

    wnorm_kernel<<<dim3(NC), dim3(64), 0, stream>>>(weight, wn, out);
    arcloss_kernel<<<dim3(NB / 128), dim3(256), 0, stream>>>(predict, target, wn, out);
}

// Round 3
// 154.098 us; speedup vs baseline: 1.0612x; 1.0612x over previous
//
#include <hip/hip_runtime.h>
#include <hip/hip_bf16.h>
#include <math.h>

// Problem constants
#define NB 131072
#define NC 128
#define NE 128
__device__ constexpr float S_    = 100.0f;
__device__ constexpr float COSM_ = 0.5403023058681398f;   // cos(1)
__device__ constexpr float SINM_ = 0.8414709848078965f;   // sin(1)
__device__ constexpr float TH_   = -0.5403023058681398f;  // cos(pi-1)
__device__ constexpr float MM_   = 0.8414709848078965f;   // sin(pi-1)*1

using short8 = __attribute__((ext_vector_type(8))) short;
using f32x4  = __attribute__((ext_vector_type(4))) float;

// fp32 -> bf16 (RNE) on raw bits (scalar path, kernel 1 only)
__device__ __forceinline__ unsigned int bf1(float f) {
    unsigned int u = __float_as_uint(f);
    return (u + 0x7FFFu + ((u >> 16) & 1u)) >> 16;
}

// packed fp32x2 -> bf16x2 (v_cvt_pk_bf16_f32)
__device__ __forceinline__ unsigned int pk2(float a, float b) {
    __hip_bfloat162 h = __float22bfloat162_rn(make_float2(a, b));
    union { __hip_bfloat162 h; unsigned int u; } cv; cv.h = h; return cv.u;
}

// Kernel 1: normalize weight rows -> bf16 (packed 2/uint) in ws; zero d_out.
__global__ void wnorm_kernel(const float* __restrict__ w,
                             unsigned int* __restrict__ wn,
                             float* __restrict__ out) {
    const int row = blockIdx.x;      // 128 rows
    const int lane = threadIdx.x;    // 64 lanes
    float2 v = ((const float2*)w)[row * 64 + lane];
    float ss = v.x * v.x + v.y * v.y;
    #pragma unroll
    for (int m = 1; m < 64; m <<= 1) ss += __shfl_xor(ss, m, 64);
    float sc = 1.0f / fmaxf(sqrtf(ss), 1e-12f);
    wn[row * 64 + lane] = bf1(v.x * sc) | (bf1(v.y * sc) << 16);
    if (row == 0 && lane == 0) *out = 0.0f;
}

// Kernel 2: fused cosine GEMM (bf16 MFMA, A-frags in registers) + arc-margin + NLL
__global__ __launch_bounds__(256, 3)
void arcloss_kernel(const float* __restrict__ predict,
                    const float* __restrict__ target,
                    const unsigned int* __restrict__ wn,
                    float* __restrict__ out) {
    constexpr int PITCH = 136;  // ushorts per LDS row (272 B) — breaks pow2 bank stride
    __shared__ __align__(16) unsigned short sw[128 * PITCH]; // wn, bf16 (~34.8 KB)
    __shared__ int   slab[128];
    __shared__ float swsum[4];

    const int t    = threadIdx.x;
    const int lane = t & 63;
    const int wv   = t >> 6;           // wave 0..3
    const int l15  = lane & 15;
    const int quad = lane >> 4;
    const long rowbase = (long)blockIdx.x * 128;

    // ---- Stage wn (32 KB, L2-hot) into padded LDS: 2 threads/row, 8 uint4 each ----
    {
        int row = t >> 1, half = t & 1;
        const uint4* src = (const uint4*)(wn + row * 64 + half * 32);
        uint4* dst = (uint4*)(sw + row * PITCH + half * 64);
        #pragma unroll
        for (int j = 0; j < 8; ++j) dst[j] = src[j];
    }

    // ---- Label scan: label = sum(target[c]*c) (one-hot), 2 threads/row ----
    {
        int row = t >> 1, half = t & 1;
        const float4* trow = (const float4*)(target + (rowbase + row) * NC + half * 64);
        float lf = 0.f;
        #pragma unroll
        for (int i = 0; i < 16; ++i) {
            float4 tv = trow[i];
            float c0 = (float)(half * 64 + i * 4);
            lf = fmaf(tv.x, c0, lf);
            lf = fmaf(tv.y, c0 + 1.f, lf);
            lf = fmaf(tv.z, c0 + 2.f, lf);
            lf = fmaf(tv.w, c0 + 3.f, lf);
        }
        lf += __shfl_xor(lf, 1, 64);
        if (half == 0) slab[row] = (int)(lf + 0.5f);
    }

    // ---- Predict: load directly in MFMA A-fragment layout, raw->bf16; rownorm deferred ----
    // A[m=l15][k=quad*8+j], kc chunks of 32. sc applied to accumulator later.
    short8 afrag[2][4];
    float sc[2];
    #pragma unroll
    for (int rt = 0; rt < 2; ++rt) {
        const float* prow = predict + (rowbase + wv * 32 + rt * 16 + l15) * NE + quad * 8;
        float ss = 0.f;
        #pragma unroll
        for (int kc = 0; kc < 4; ++kc) {
            float4 p0 = *(const float4*)(prow + kc * 32);
            float4 p1 = *(const float4*)(prow + kc * 32 + 4);
            ss += p0.x * p0.x + p0.y * p0.y + p0.z * p0.z + p0.w * p0.w;
            ss += p1.x * p1.x + p1.y * p1.y + p1.z * p1.z + p1.w * p1.w;
            union { short8 s8; unsigned int u[4]; } uu;
            uu.u[0] = pk2(p0.x, p0.y);
            uu.u[1] = pk2(p0.z, p0.w);
            uu.u[2] = pk2(p1.x, p1.y);
            uu.u[3] = pk2(p1.z, p1.w);
            afrag[rt][kc] = uu.s8;
        }
        // lanes {l15, +16, +32, +48} hold the same row's k-chunks
        ss += __shfl_xor(ss, 16, 64);
        ss += __shfl_xor(ss, 32, 64);
        sc[rt] = 1.0f / fmaxf(sqrtf(ss), 1e-12f);
    }
    __syncthreads();

    // ---- MFMA: each wave computes 32 rows x 128 classes ----
    f32x4 acc[2][8];
    #pragma unroll
    for (int rt = 0; rt < 2; ++rt)
        #pragma unroll
        for (int tc = 0; tc < 8; ++tc)
            acc[rt][tc] = (f32x4){0.f, 0.f, 0.f, 0.f};

    #pragma unroll
    for (int tc = 0; tc < 8; ++tc) {
        short8 b[4];
        #pragma unroll
        for (int kc = 0; kc < 4; ++kc)
            b[kc] = *(const short8*)(sw + (tc * 16 + l15) * PITCH + kc * 32 + quad * 8);
        #pragma unroll
        for (int kc = 0; kc < 4; ++kc) {
            acc[0][tc] = __builtin_amdgcn_mfma_f32_16x16x32_bf16(afrag[0][kc], b[kc], acc[0][tc], 0, 0, 0);
            acc[1][tc] = __builtin_amdgcn_mfma_f32_16x16x32_bf16(afrag[1][kc], b[kc], acc[1][tc], 0, 0, 0);
        }
    }

    // ---- Epilogue: scale by 1/||x||, margin at label class only, logsumexp NLL ----
    float lsum = 0.0f;
    #pragma unroll
    for (int rt = 0; rt < 2; ++rt) {
        #pragma unroll
        for (int v = 0; v < 4; ++v) {
            const int rl  = quad * 4 + v;                 // row within 16-tile (C/D: quad*4+reg)
            const int lab = slab[wv * 32 + rt * 16 + rl];
            const float scv = __shfl(sc[rt], rl, 64);     // sc held by lane rl (quad-0 group)
            const bool own  = (l15 == (lab & 15));
            const int  tcl  = lab >> 4;
            float cv[8];
            float mx = -1e30f, cl = 0.f;
            #pragma unroll
            for (int tc = 0; tc < 8; ++tc) {
                float ci = acc[rt][tc][v] * scv;
                cv[tc] = ci;
                mx = fmaxf(mx, ci);
                cl += (own && tc == tcl) ? ci : 0.f;
            }
            #pragma unroll
            for (int m = 1; m < 16; m <<= 1) mx = fmaxf(mx, __shfl_xor(mx, m, 64));
            // phi for the label class (garbage-but-finite on non-owning lanes, masked below)
            float s2 = fmaxf(1.0f - cl * cl, 0.0f);
            float ph = cl * COSM_ - sqrtf(s2) * SINM_;
            ph = (cl > TH_) ? ph : (cl - MM_);
            float Smx = S_ * mx;   // stabilizer: max over raw cosines (>= max incl. phi)
            float se = 0.f;
            #pragma unroll
            for (int tc = 0; tc < 8; ++tc) se += __expf(fmaf(S_, cv[tc], -Smx));
            float d  = __expf(fmaf(S_, ph, -Smx)) - __expf(fmaf(S_, cl, -Smx));
            se += own ? d : 0.f;
            float lv = own ? S_ * ph : 0.f;
            #pragma unroll
            for (int m = 1; m < 16; m <<= 1) {
                se += __shfl_xor(se, m, 64);
                lv += __shfl_xor(lv, m, 64);
            }
            if (l15 == 0) lsum += __logf(se) + Smx - lv;
        }
    }

    // ---- Block reduction + one atomic per block ----
    #pragma unroll
    for (int m = 1; m < 64; m <<= 1) lsum += __shfl_xor(lsum, m, 64);
    if (lane == 0) swsum[wv] = lsum;
    __syncthreads();
    if (t == 0) {
        float tot = swsum[0] + swsum[1] + swsum[2] + swsum[3];
        atomicAdd(out, tot * (1.0f / (float)NB));
    }
}

extern "C" void kernel_launch(void* const* d_in, const int* in_sizes, int n_in,
                              void* d_out, int out_size, void* d_ws, size_t ws_size,
                              hipStream_t stream) {
    const float* predict = (const float*)d_in[0];
    const float* target  = (const float*)d_in[1];
    const float* weight  = (const float*)d_in[2];
    float* out = (float*)d_out;
    unsigned int* wn = (unsigned int*)d_ws;  // 128*64 uints = 32 KB bf16 wn

    wnorm_kernel<<<dim3(NC), dim3(64), 0, stream>>>(weight, wn, out);
    arcloss_kernel<<<dim3(NB / 128), dim3(256), 0, stream>>>(predict, target, wn, out);
}